// Round 11
// baseline (798.466 us; speedup 1.0000x reference)
//
#include <hip/hip_runtime.h>
#include <hip/hip_bf16.h>

#define NN 50000
#define EE 800000
#define FF 144

typedef __hip_bfloat16 bf16;
typedef __attribute__((ext_vector_type(4))) float floatx4;

// ---------------- edge_index int64-layout detection ----------------

__global__ void detect_k(const int* __restrict__ ei, int* __restrict__ flag) {
    __shared__ int nz;
    if (threadIdx.x == 0) nz = 0;
    __syncthreads();
    if (ei[2 * threadIdx.x + 1] != 0) atomicAdd(&nz, 1);
    __syncthreads();
    if (threadIdx.x == 0) *flag = (nz == 0) ? 1 : 0;
}

__device__ inline void load_edge(const int* ei, int e, int flag, int& r, int& c) {
    if (flag) { r = ei[2 * e]; c = ei[2 * EE + 2 * e]; }
    else      { r = ei[e];     c = ei[EE + e]; }
}

// ---------------- x fp32 -> bf16 (layout preserved, C-order (N,F)) ----------------

__global__ void cvt_k(const float* __restrict__ x, bf16* __restrict__ xb) {
    int t = blockIdx.x * 256 + threadIdx.x;
    if (t >= NN * FF) return;
    xb[t] = (bf16)x[t];
}

// ---------------- graph preprocessing ----------------

__global__ void hist_k(const int* __restrict__ ei, int* __restrict__ cnt,
                       const int* __restrict__ flagp) {
    int flag = *flagp;
    int e = blockIdx.x * 256 + threadIdx.x;
    if (e >= EE) return;
    int r, c; load_edge(ei, e, flag, r, c);
    if (r != c) atomicAdd(&cnt[r], 1);
}

__global__ void dinv_k(const int* __restrict__ cnt, float* __restrict__ dinv) {
    int i = blockIdx.x * 256 + threadIdx.x;
    if (i >= NN) return;
    int c = cnt[i];
    dinv[i] = c > 0 ? rsqrtf((float)c) : 0.f;
}

__global__ void scan_k(const int* __restrict__ cnt, int* __restrict__ rowptr) {
    __shared__ int wsum[16];
    int tid = threadIdx.x;
    int wv = tid >> 6, ln = tid & 63;
    int running = 0;
    for (int base = 0; base < NN; base += 1024) {
        __syncthreads();
        int i = base + tid;
        int v = (i < NN) ? cnt[i] : 0;
        int x = v;
        #pragma unroll
        for (int off = 1; off < 64; off <<= 1) {
            int t = __shfl_up(x, off, 64);
            if (ln >= off) x += t;
        }
        if (ln == 63) wsum[wv] = x;
        __syncthreads();
        if (wv == 0) {
            int w = (ln < 16) ? wsum[ln] : 0;
            #pragma unroll
            for (int off = 1; off < 16; off <<= 1) {
                int t = __shfl_up(w, off, 64);
                if (ln >= off) w += t;
            }
            if (ln < 16) wsum[ln] = w;
        }
        __syncthreads();
        int wexcl = wv ? wsum[wv - 1] : 0;
        if (i < NN) rowptr[i] = running + wexcl + (x - v);
        running += wsum[15];
    }
    if (tid == 0) rowptr[NN] = running;
}

__global__ void scatter_k(const int* __restrict__ ei, const float* __restrict__ w,
                          const float* __restrict__ dinv, const int* __restrict__ rowptr,
                          int* __restrict__ fill, int* __restrict__ cols,
                          float* __restrict__ lap, const int* __restrict__ flagp) {
    int flag = *flagp;
    int e = blockIdx.x * 256 + threadIdx.x;
    if (e >= EE) return;
    int r, c; load_edge(ei, e, flag, r, c);
    if (r == c) return;
    int pos = rowptr[r] + atomicAdd(&fill[r], 1);
    cols[pos] = c;
    lap[pos] = -dinv[r] * dinv[c] * w[e];
}

// ---------------- SpMM (node-major) ----------------

template <int MODE>
__global__ void spmm_k(const bf16* __restrict__ v, const bf16* __restrict__ x0,
                       const int* __restrict__ rowptr, const int* __restrict__ cols,
                       const float* __restrict__ lap, bf16* __restrict__ y) {
    int t = blockIdx.x * 256 + threadIdx.x;
    if (t >= NN * FF) return;
    int i = t / FF;
    int f = t - i * FF;
    float acc = 0.f;
    int s = rowptr[i], e = rowptr[i + 1];
    for (int p = s; p < e; ++p)
        acc = fmaf(lap[p], (float)v[cols[p] * FF + f], acc);
    if (MODE == 1) acc = 2.f * acc - (float)x0[t];
    y[t] = (bf16)acc;
}

// ---------------- fp32 VALU GEMM: accb[n][o] (+)= sum_i A[n][i] * W[KIDX][i][o] ----------------
// Documented C-order weight (K, F_IN, F_OUT): W_k[i][o] = wt[KIDX*20736 + i*144 + o].

__device__ inline floatx4 loadA4(const bf16* A, int r, int k4, bool valid) {
    floatx4 z = {0.f, 0.f, 0.f, 0.f};
    if (!valid) return z;
    const unsigned short* p = (const unsigned short*)A + r * 144 + k4 * 4;
    uint2 u = *(const uint2*)p;
    floatx4 o;
    o.x = __uint_as_float((u.x & 0xffffu) << 16);
    o.y = __uint_as_float(u.x & 0xffff0000u);
    o.z = __uint_as_float((u.y & 0xffffu) << 16);
    o.w = __uint_as_float(u.y & 0xffff0000u);
    return o;
}

template <int FIRST, int KIDX>
__global__ __launch_bounds__(256)
void vgemm_k(const bf16* __restrict__ A, const float* __restrict__ wt,
             float* __restrict__ accb) {
    __shared__ floatx4 Wlds[72 * 36];
    int tid = threadIdx.x;
    const floatx4* Wg = (const floatx4*)(wt + KIDX * 144 * 144);  // [i][o] row-major

    int pr = tid >> 2;
    int cq = tid & 3;
    int r0 = blockIdx.x * 128 + pr * 2;
    int r1 = r0 + 1;
    bool v0 = r0 < NN, v1 = r1 < NN;

    floatx4 acc0[9], acc1[9];
    floatx4 z = {0.f, 0.f, 0.f, 0.f};
    #pragma unroll
    for (int q = 0; q < 9; ++q) { acc0[q] = z; acc1[q] = z; }

    for (int ph = 0; ph < 2; ++ph) {
        __syncthreads();
        for (int q = tid; q < 72 * 36; q += 256)
            Wlds[q] = Wg[ph * 72 * 36 + q];
        __syncthreads();

        #pragma unroll 2
        for (int k4 = 0; k4 < 18; ++k4) {
            int kg = ph * 18 + k4;
            floatx4 a0 = loadA4(A, r0, kg, v0);
            floatx4 a1 = loadA4(A, r1, kg, v1);
            #pragma unroll
            for (int kk = 0; kk < 4; ++kk) {
                float s0 = (kk == 0) ? a0.x : (kk == 1) ? a0.y : (kk == 2) ? a0.z : a0.w;
                float s1 = (kk == 0) ? a1.x : (kk == 1) ? a1.y : (kk == 2) ? a1.z : a1.w;
                const floatx4* wrow = &Wlds[(k4 * 4 + kk) * 36 + cq * 9];
                #pragma unroll
                for (int q = 0; q < 9; ++q) {
                    floatx4 w = wrow[q];
                    acc0[q] += s0 * w;
                    acc1[q] += s1 * w;
                }
            }
        }
    }

    int n0 = cq * 36;
    if (v0) {
        floatx4* o = (floatx4*)(accb + r0 * 144 + n0);
        #pragma unroll
        for (int q = 0; q < 9; ++q) { if (FIRST) o[q] = acc0[q]; else o[q] += acc0[q]; }
    }
    if (v1) {
        floatx4* o = (floatx4*)(accb + r1 * 144 + n0);
        #pragma unroll
        for (int q = 0; q < 9; ++q) { if (FIRST) o[q] = acc1[q]; else o[q] += acc1[q]; }
    }
}

// ---------------- final: out (FLOAT32!) = accb + bias ----------------

__global__ void final_k(const float* __restrict__ accb, const float* __restrict__ bias,
                        float* __restrict__ out) {
    int t = blockIdx.x * 256 + threadIdx.x;
    if (t >= NN * FF) return;
    int f = t % FF;
    out[t] = accb[t] + bias[f];
}

// ---------------- launch ----------------

extern "C" void kernel_launch(void* const* d_in, const int* in_sizes, int n_in,
                              void* d_out, int out_size, void* d_ws, size_t ws_size,
                              hipStream_t stream) {
    int ix = -1, iei = -1, iew = -1, iwt = -1, ib = -1;
    for (int i = 0; i < n_in; ++i) {
        switch (in_sizes[i]) {
            case NN * FF:      if (ix  < 0) ix  = i; break;
            case 2 * EE:       if (iei < 0) iei = i; break;
            case EE:           if (iew < 0) iew = i; break;
            case 3 * FF * FF:  if (iwt < 0) iwt = i; break;
            case FF:           if (ib  < 0) ib  = i; break;
        }
    }
    if (ix < 0 || iei < 0 || iew < 0 || iwt < 0 || ib < 0) {
        ix = 0; iei = 1; iew = 2; iwt = 3; ib = 4;
    }
    const float* x    = (const float*)d_in[ix];
    const int*   ei   = (const int*)d_in[iei];
    const float* ew   = (const float*)d_in[iew];
    const float* wt   = (const float*)d_in[iwt];
    const float* bias = (const float*)d_in[ib];
    float* out = (float*)d_out;   // reference output dtype is float32

    char* p = (char*)d_ws;
    int*   cnt    = (int*)(p + 0);
    int*   fill   = (int*)(p + 200000);
    int*   rowptr = (int*)(p + 400000);
    float* dinv   = (float*)(p + 600016);
    int*   cols   = (int*)(p + 800016);
    float* lap    = (float*)(p + 4000016);
    bf16*  tx1    = (bf16*)(p + 7200016);
    bf16*  tx2    = (bf16*)(p + 21600016);
    float* accb   = (float*)(p + 36000016);
    bf16*  xb     = (bf16*)(p + 64800016);
    int*   eflag  = (int*)(p + 79200016);

    if (ws_size < 79200032) return;

    hipMemsetAsync(d_ws, 0, 400000, stream);

    int ewGrid   = (NN * FF + 255) / 256;
    int gemmGrid = (NN + 127) / 128;

    detect_k<<<1, 256, 0, stream>>>(ei, eflag);
    cvt_k<<<ewGrid, 256, 0, stream>>>(x, xb);
    hist_k<<<(EE + 255) / 256, 256, 0, stream>>>(ei, cnt, eflag);
    dinv_k<<<(NN + 255) / 256, 256, 0, stream>>>(cnt, dinv);
    scan_k<<<1, 1024, 0, stream>>>(cnt, rowptr);
    scatter_k<<<(EE + 255) / 256, 256, 0, stream>>>(ei, ew, dinv, rowptr, fill, cols, lap, eflag);

    vgemm_k<1, 0><<<gemmGrid, 256, 0, stream>>>(xb, wt, accb);
    spmm_k<0><<<ewGrid, 256, 0, stream>>>(xb, xb, rowptr, cols, lap, tx1);
    vgemm_k<0, 1><<<gemmGrid, 256, 0, stream>>>(tx1, wt, accb);
    spmm_k<1><<<ewGrid, 256, 0, stream>>>(tx1, xb, rowptr, cols, lap, tx2);
    vgemm_k<0, 2><<<gemmGrid, 256, 0, stream>>>(tx2, wt, accb);
    final_k<<<ewGrid, 256, 0, stream>>>(accb, bias, out);
}

// Round 12
// 377.840 us; speedup vs baseline: 2.1132x; 2.1132x over previous
//
#include <hip/hip_runtime.h>
#include <hip/hip_bf16.h>

#define NN 50000
#define EE 800000
#define FF 144

typedef __hip_bfloat16 bf16;
typedef __attribute__((ext_vector_type(8))) short short8;
typedef __attribute__((ext_vector_type(4))) float floatx4;

__device__ inline float blo(unsigned x) { return __uint_as_float(x << 16); }
__device__ inline float bhi(unsigned x) { return __uint_as_float(x & 0xffff0000u); }

// ---------------- edge_index int64-layout detection ----------------

__global__ void detect_k(const int* __restrict__ ei, int* __restrict__ flag) {
    __shared__ int nz;
    if (threadIdx.x == 0) nz = 0;
    __syncthreads();
    if (ei[2 * threadIdx.x + 1] != 0) atomicAdd(&nz, 1);
    __syncthreads();
    if (threadIdx.x == 0) *flag = (nz == 0) ? 1 : 0;
}

__device__ inline void load_edge(const int* ei, int e, int flag, int& r, int& c) {
    if (flag) { r = ei[2 * e]; c = ei[2 * EE + 2 * e]; }
    else      { r = ei[e];     c = ei[EE + e]; }
}

// ---------------- x fp32 -> bf16 (C-order (N,F) preserved) ----------------

__global__ void cvt_k(const float* __restrict__ x, bf16* __restrict__ xb) {
    int t = blockIdx.x * 256 + threadIdx.x;
    if (t >= NN * FF) return;
    xb[t] = (bf16)x[t];
}

// ---------------- graph preprocessing ----------------

__global__ void hist_k(const int* __restrict__ ei, int* __restrict__ cnt,
                       const int* __restrict__ flagp) {
    int flag = *flagp;
    int e = blockIdx.x * 256 + threadIdx.x;
    if (e >= EE) return;
    int r, c; load_edge(ei, e, flag, r, c);
    if (r != c) atomicAdd(&cnt[r], 1);
}

__global__ void dinv_k(const int* __restrict__ cnt, float* __restrict__ dinv) {
    int i = blockIdx.x * 256 + threadIdx.x;
    if (i >= NN) return;
    int c = cnt[i];
    dinv[i] = c > 0 ? rsqrtf((float)c) : 0.f;
}

__global__ void scan_k(const int* __restrict__ cnt, int* __restrict__ rowptr) {
    __shared__ int wsum[16];
    int tid = threadIdx.x;
    int wv = tid >> 6, ln = tid & 63;
    int running = 0;
    for (int base = 0; base < NN; base += 1024) {
        __syncthreads();
        int i = base + tid;
        int v = (i < NN) ? cnt[i] : 0;
        int x = v;
        #pragma unroll
        for (int off = 1; off < 64; off <<= 1) {
            int t = __shfl_up(x, off, 64);
            if (ln >= off) x += t;
        }
        if (ln == 63) wsum[wv] = x;
        __syncthreads();
        if (wv == 0) {
            int w = (ln < 16) ? wsum[ln] : 0;
            #pragma unroll
            for (int off = 1; off < 16; off <<= 1) {
                int t = __shfl_up(w, off, 64);
                if (ln >= off) w += t;
            }
            if (ln < 16) wsum[ln] = w;
        }
        __syncthreads();
        int wexcl = wv ? wsum[wv - 1] : 0;
        if (i < NN) rowptr[i] = running + wexcl + (x - v);
        running += wsum[15];
    }
    if (tid == 0) rowptr[NN] = running;
}

__global__ void scatter_k(const int* __restrict__ ei, const float* __restrict__ w,
                          const float* __restrict__ dinv, const int* __restrict__ rowptr,
                          int* __restrict__ fill, int* __restrict__ cols,
                          float* __restrict__ lap, const int* __restrict__ flagp) {
    int flag = *flagp;
    int e = blockIdx.x * 256 + threadIdx.x;
    if (e >= EE) return;
    int r, c; load_edge(ei, e, flag, r, c);
    if (r == c) return;
    int pos = rowptr[r] + atomicAdd(&fill[r], 1);
    cols[pos] = c;
    lap[pos] = -dinv[r] * dinv[c] * w[e];
}

// ---------------- SpMM 8-wide: thread = (node, f-octet) ----------------
// 18 threads/node, 16B gathers; y = spmm(v) (MODE 0) or 2*spmm(v) - x0 (MODE 1).

template <int MODE>
__global__ void spmm_k(const bf16* __restrict__ v, const bf16* __restrict__ x0,
                       const int* __restrict__ rowptr, const int* __restrict__ cols,
                       const float* __restrict__ lap, bf16* __restrict__ y) {
    int t = blockIdx.x * 256 + threadIdx.x;
    if (t >= NN * 18) return;
    int i = t / 18;
    int f8 = (t - i * 18) * 8;
    const unsigned short* vp = (const unsigned short*)v + f8;

    float a[8];
    #pragma unroll
    for (int j = 0; j < 8; ++j) a[j] = 0.f;

    int s = rowptr[i], e = rowptr[i + 1];
    for (int p = s; p < e; ++p) {
        float l = lap[p];
        uint4 u = *(const uint4*)(vp + cols[p] * FF);
        a[0] = fmaf(l, blo(u.x), a[0]);
        a[1] = fmaf(l, bhi(u.x), a[1]);
        a[2] = fmaf(l, blo(u.y), a[2]);
        a[3] = fmaf(l, bhi(u.y), a[3]);
        a[4] = fmaf(l, blo(u.z), a[4]);
        a[5] = fmaf(l, bhi(u.z), a[5]);
        a[6] = fmaf(l, blo(u.w), a[6]);
        a[7] = fmaf(l, bhi(u.w), a[7]);
    }

    if (MODE == 1) {
        uint4 u0 = *(const uint4*)((const unsigned short*)x0 + i * FF + f8);
        a[0] = 2.f * a[0] - blo(u0.x);  a[1] = 2.f * a[1] - bhi(u0.x);
        a[2] = 2.f * a[2] - blo(u0.y);  a[3] = 2.f * a[3] - bhi(u0.y);
        a[4] = 2.f * a[4] - blo(u0.z);  a[5] = 2.f * a[5] - bhi(u0.z);
        a[6] = 2.f * a[6] - blo(u0.w);  a[7] = 2.f * a[7] - bhi(u0.w);
    }

    unsigned short rs[8];
    #pragma unroll
    for (int j = 0; j < 8; ++j) {
        bf16 b = (bf16)a[j];
        rs[j] = *(unsigned short*)&b;
    }
    *(uint4*)((unsigned short*)y + i * FF + f8) = *(uint4*)rs;
}

// ---------------- fused MFMA GEMM: out[n][o] = sum_ph Tx_ph @ W[ph] + bias ----------------
// 256 thr = 4 waves; wave = 16 rows x 144 cols (9 16x16 C-tiles), K = 144 -> 5 x 32 (zero-pad).
// W[ph] is (i,o) C-order; staged transposed in LDS: Wt[o*168 + i] (bf16), i in [0,160) zero-padded.
// Fragment maps (HW-verified r2==r4 bit-identical + guide m89/m91):
//   A[m=lane&15][k=quad*8+j], B[n=lane&15][k=quad*8+j] (from Wt row o), C: col=lane&15,row=quad*4+reg.

__global__ __launch_bounds__(256)
void gemm_fused(const bf16* __restrict__ A0, const bf16* __restrict__ A1,
                const bf16* __restrict__ A2, const float* __restrict__ wt,
                const float* __restrict__ bias, float* __restrict__ out) {
    __shared__ __align__(16) short Wt[144 * 168];
    int tid = threadIdx.x;
    int wv = tid >> 6, ln = tid & 63;
    int m16 = ln & 15, quad = ln >> 4;
    int rowBase = blockIdx.x * 64 + wv * 16;
    int row = rowBase + m16;

    const bf16* const srcs[3] = {A0, A1, A2};
    const short8 zero8 = {0, 0, 0, 0, 0, 0, 0, 0};

    floatx4 acc[9];
    #pragma unroll
    for (int q = 0; q < 9; ++q) acc[q] = (floatx4){0.f, 0.f, 0.f, 0.f};

    #pragma unroll
    for (int ph = 0; ph < 3; ++ph) {
        __syncthreads();   // previous phase's readers done
        const float* W = wt + ph * FF * FF;
        for (int e = tid; e < FF * FF; e += 256) {
            int i = e / FF, o = e - i * FF;
            bf16 b = (bf16)W[e];
            Wt[o * 168 + i] = *(const short*)&b;
        }
        for (int e = tid; e < FF * 16; e += 256) {
            int o = e % FF;
            int i = FF + e / FF;
            Wt[o * 168 + i] = 0;
        }
        __syncthreads();

        const bf16* A = srcs[ph];
        short8 a[5];
        #pragma unroll
        for (int kt = 0; kt < 5; ++kt) {
            int k0 = kt * 32 + quad * 8;
            if (k0 < FF && row < NN)
                a[kt] = *(const short8*)((const short*)A + row * FF + k0);
            else
                a[kt] = zero8;
        }

        #pragma unroll
        for (int nt = 0; nt < 9; ++nt) {
            #pragma unroll
            for (int kt = 0; kt < 5; ++kt) {
                short8 b = *(const short8*)&Wt[(nt * 16 + m16) * 168 + kt * 32 + quad * 8];
                acc[nt] = __builtin_amdgcn_mfma_f32_16x16x32_bf16(a[kt], b, acc[nt], 0, 0, 0);
            }
        }
    }

    int rowc = rowBase + quad * 4;
    #pragma unroll
    for (int nt = 0; nt < 9; ++nt) {
        int col = nt * 16 + m16;
        float bs = bias[col];
        #pragma unroll
        for (int r = 0; r < 4; ++r) {
            int rr = rowc + r;
            if (rr < NN) out[rr * FF + col] = acc[nt][r] + bs;
        }
    }
}

// ---------------- launch ----------------

extern "C" void kernel_launch(void* const* d_in, const int* in_sizes, int n_in,
                              void* d_out, int out_size, void* d_ws, size_t ws_size,
                              hipStream_t stream) {
    int ix = -1, iei = -1, iew = -1, iwt = -1, ib = -1;
    for (int i = 0; i < n_in; ++i) {
        switch (in_sizes[i]) {
            case NN * FF:      if (ix  < 0) ix  = i; break;
            case 2 * EE:       if (iei < 0) iei = i; break;
            case EE:           if (iew < 0) iew = i; break;
            case 3 * FF * FF:  if (iwt < 0) iwt = i; break;
            case FF:           if (ib  < 0) ib  = i; break;
        }
    }
    if (ix < 0 || iei < 0 || iew < 0 || iwt < 0 || ib < 0) {
        ix = 0; iei = 1; iew = 2; iwt = 3; ib = 4;
    }
    const float* x    = (const float*)d_in[ix];
    const int*   ei   = (const int*)d_in[iei];
    const float* ew   = (const float*)d_in[iew];
    const float* wt   = (const float*)d_in[iwt];
    const float* bias = (const float*)d_in[ib];
    float* out = (float*)d_out;   // reference output dtype is float32

    char* p = (char*)d_ws;
    int*   cnt    = (int*)(p + 0);
    int*   fill   = (int*)(p + 200000);
    int*   rowptr = (int*)(p + 400000);
    float* dinv   = (float*)(p + 600016);
    int*   cols   = (int*)(p + 800016);
    float* lap    = (float*)(p + 4000016);
    bf16*  tx1    = (bf16*)(p + 7200016);
    bf16*  tx2    = (bf16*)(p + 21600016);
    bf16*  xb     = (bf16*)(p + 64800016);
    int*   eflag  = (int*)(p + 79200016);

    if (ws_size < 79200032) return;

    hipMemsetAsync(d_ws, 0, 400000, stream);  // cnt + fill

    int ewGrid   = (NN * FF + 255) / 256;
    int spGrid   = (NN * 18 + 255) / 256;
    int gemmGrid = (NN + 63) / 64;

    detect_k<<<1, 256, 0, stream>>>(ei, eflag);
    cvt_k<<<ewGrid, 256, 0, stream>>>(x, xb);
    hist_k<<<(EE + 255) / 256, 256, 0, stream>>>(ei, cnt, eflag);
    dinv_k<<<(NN + 255) / 256, 256, 0, stream>>>(cnt, dinv);
    scan_k<<<1, 1024, 0, stream>>>(cnt, rowptr);
    scatter_k<<<(EE + 255) / 256, 256, 0, stream>>>(ei, ew, dinv, rowptr, fill, cols, lap, eflag);

    spmm_k<0><<<spGrid, 256, 0, stream>>>(xb, xb, rowptr, cols, lap, tx1);
    spmm_k<1><<<spGrid, 256, 0, stream>>>(tx1, xb, rowptr, cols, lap, tx2);
    gemm_fused<<<gemmGrid, 256, 0, stream>>>(xb, tx1, tx2, wt, bias, out);
}

// Round 13
// 353.828 us; speedup vs baseline: 2.2566x; 1.0679x over previous
//
#include <hip/hip_runtime.h>
#include <hip/hip_bf16.h>

#define NN 50000
#define EE 800000
#define FF 144

typedef __hip_bfloat16 bf16;
typedef __attribute__((ext_vector_type(8))) short short8;
typedef __attribute__((ext_vector_type(4))) float floatx4;

__device__ inline float blo(unsigned x) { return __uint_as_float(x << 16); }
__device__ inline float bhi(unsigned x) { return __uint_as_float(x & 0xffff0000u); }

// ---------------- edge_index int64-layout detection ----------------

__global__ void detect_k(const int* __restrict__ ei, int* __restrict__ flag) {
    __shared__ int nz;
    if (threadIdx.x == 0) nz = 0;
    __syncthreads();
    if (ei[2 * threadIdx.x + 1] != 0) atomicAdd(&nz, 1);
    __syncthreads();
    if (threadIdx.x == 0) *flag = (nz == 0) ? 1 : 0;
}

__device__ inline void load_edge(const int* ei, int e, int flag, int& r, int& c) {
    if (flag) { r = ei[2 * e]; c = ei[2 * EE + 2 * e]; }
    else      { r = ei[e];     c = ei[EE + e]; }
}

// ---------------- x fp32 -> bf16 (C-order (N,F) preserved) ----------------

__global__ void cvt_k(const float* __restrict__ x, bf16* __restrict__ xb) {
    int t = blockIdx.x * 256 + threadIdx.x;
    if (t >= NN * FF) return;
    xb[t] = (bf16)x[t];
}

// ---------------- W fp32 (K,i,o) -> bf16 transposed padded image wtb[ph][o][i] ----------------
// wtb stride 168 shorts per o-row; i in [144,168) zeroed. One-time cost, removes all
// per-block convert+transpose work (the 6.76M bank conflicts) from gemm_fused.

__global__ void cvtw_k(const float* __restrict__ wt, short* __restrict__ wtb) {
    int t = blockIdx.x * 256 + threadIdx.x;
    if (t >= 3 * FF * 168) return;
    int ph = t / (FF * 168);
    int rem = t - ph * FF * 168;
    int o = rem / 168;
    int i = rem - o * 168;
    short v = 0;
    if (i < FF) {
        bf16 b = (bf16)wt[ph * FF * FF + i * FF + o];
        v = *(const short*)&b;
    }
    wtb[t] = v;
}

// ---------------- graph preprocessing ----------------

__global__ void hist_k(const int* __restrict__ ei, int* __restrict__ cnt,
                       const int* __restrict__ flagp) {
    int flag = *flagp;
    int e = blockIdx.x * 256 + threadIdx.x;
    if (e >= EE) return;
    int r, c; load_edge(ei, e, flag, r, c);
    if (r != c) atomicAdd(&cnt[r], 1);
}

__global__ void dinv_k(const int* __restrict__ cnt, float* __restrict__ dinv) {
    int i = blockIdx.x * 256 + threadIdx.x;
    if (i >= NN) return;
    int c = cnt[i];
    dinv[i] = c > 0 ? rsqrtf((float)c) : 0.f;
}

__global__ void scan_k(const int* __restrict__ cnt, int* __restrict__ rowptr) {
    __shared__ int wsum[16];
    int tid = threadIdx.x;
    int wv = tid >> 6, ln = tid & 63;
    int running = 0;
    for (int base = 0; base < NN; base += 1024) {
        __syncthreads();
        int i = base + tid;
        int v = (i < NN) ? cnt[i] : 0;
        int x = v;
        #pragma unroll
        for (int off = 1; off < 64; off <<= 1) {
            int t = __shfl_up(x, off, 64);
            if (ln >= off) x += t;
        }
        if (ln == 63) wsum[wv] = x;
        __syncthreads();
        if (wv == 0) {
            int w = (ln < 16) ? wsum[ln] : 0;
            #pragma unroll
            for (int off = 1; off < 16; off <<= 1) {
                int t = __shfl_up(w, off, 64);
                if (ln >= off) w += t;
            }
            if (ln < 16) wsum[ln] = w;
        }
        __syncthreads();
        int wexcl = wv ? wsum[wv - 1] : 0;
        if (i < NN) rowptr[i] = running + wexcl + (x - v);
        running += wsum[15];
    }
    if (tid == 0) rowptr[NN] = running;
}

__global__ void scatter_k(const int* __restrict__ ei, const float* __restrict__ w,
                          const float* __restrict__ dinv, const int* __restrict__ rowptr,
                          int* __restrict__ fill, int* __restrict__ cols,
                          float* __restrict__ lap, const int* __restrict__ flagp) {
    int flag = *flagp;
    int e = blockIdx.x * 256 + threadIdx.x;
    if (e >= EE) return;
    int r, c; load_edge(ei, e, flag, r, c);
    if (r == c) return;
    int pos = rowptr[r] + atomicAdd(&fill[r], 1);
    cols[pos] = c;
    lap[pos] = -dinv[r] * dinv[c] * w[e];
}

// ---------------- SpMM 8-wide, edge loop unrolled x2 ----------------

template <int MODE>
__global__ void spmm_k(const bf16* __restrict__ v, const bf16* __restrict__ x0,
                       const int* __restrict__ rowptr, const int* __restrict__ cols,
                       const float* __restrict__ lap, bf16* __restrict__ y) {
    int t = blockIdx.x * 256 + threadIdx.x;
    if (t >= NN * 18) return;
    int i = t / 18;
    int f8 = (t - i * 18) * 8;
    const unsigned short* vp = (const unsigned short*)v + f8;

    float a[8];
    #pragma unroll
    for (int j = 0; j < 8; ++j) a[j] = 0.f;

    int s = rowptr[i], e = rowptr[i + 1];
    int p = s;
    for (; p + 1 < e; p += 2) {
        int   c0 = cols[p],   c1 = cols[p + 1];
        float l0 = lap[p],    l1 = lap[p + 1];
        uint4 u0 = *(const uint4*)(vp + c0 * FF);
        uint4 u1 = *(const uint4*)(vp + c1 * FF);
        a[0] = fmaf(l0, blo(u0.x), a[0]);  a[1] = fmaf(l0, bhi(u0.x), a[1]);
        a[2] = fmaf(l0, blo(u0.y), a[2]);  a[3] = fmaf(l0, bhi(u0.y), a[3]);
        a[4] = fmaf(l0, blo(u0.z), a[4]);  a[5] = fmaf(l0, bhi(u0.z), a[5]);
        a[6] = fmaf(l0, blo(u0.w), a[6]);  a[7] = fmaf(l0, bhi(u0.w), a[7]);
        a[0] = fmaf(l1, blo(u1.x), a[0]);  a[1] = fmaf(l1, bhi(u1.x), a[1]);
        a[2] = fmaf(l1, blo(u1.y), a[2]);  a[3] = fmaf(l1, bhi(u1.y), a[3]);
        a[4] = fmaf(l1, blo(u1.z), a[4]);  a[5] = fmaf(l1, bhi(u1.z), a[5]);
        a[6] = fmaf(l1, blo(u1.w), a[6]);  a[7] = fmaf(l1, bhi(u1.w), a[7]);
    }
    if (p < e) {
        float l = lap[p];
        uint4 u = *(const uint4*)(vp + cols[p] * FF);
        a[0] = fmaf(l, blo(u.x), a[0]);  a[1] = fmaf(l, bhi(u.x), a[1]);
        a[2] = fmaf(l, blo(u.y), a[2]);  a[3] = fmaf(l, bhi(u.y), a[3]);
        a[4] = fmaf(l, blo(u.z), a[4]);  a[5] = fmaf(l, bhi(u.z), a[5]);
        a[6] = fmaf(l, blo(u.w), a[6]);  a[7] = fmaf(l, bhi(u.w), a[7]);
    }

    if (MODE == 1) {
        uint4 u0 = *(const uint4*)((const unsigned short*)x0 + i * FF + f8);
        a[0] = 2.f * a[0] - blo(u0.x);  a[1] = 2.f * a[1] - bhi(u0.x);
        a[2] = 2.f * a[2] - blo(u0.y);  a[3] = 2.f * a[3] - bhi(u0.y);
        a[4] = 2.f * a[4] - blo(u0.z);  a[5] = 2.f * a[5] - bhi(u0.z);
        a[6] = 2.f * a[6] - blo(u0.w);  a[7] = 2.f * a[7] - bhi(u0.w);
    }

    unsigned short rs[8];
    #pragma unroll
    for (int j = 0; j < 8; ++j) {
        bf16 b = (bf16)a[j];
        rs[j] = *(unsigned short*)&b;
    }
    *(uint4*)((unsigned short*)y + i * FF + f8) = *(uint4*)rs;
}

// ---------------- fused MFMA GEMM: out[n][o] = sum_ph Tx_ph @ W[ph] + bias ----------------
// Staging now = conflict-free uint4 copies from the pre-built wtb image (no convert,
// no transpose in-kernel). K-loop / fragment maps identical to the r12 passing kernel.

__global__ __launch_bounds__(256)
void gemm_fused(const bf16* __restrict__ A0, const bf16* __restrict__ A1,
                const bf16* __restrict__ A2, const short* __restrict__ wtb,
                const float* __restrict__ bias, float* __restrict__ out) {
    __shared__ __align__(16) short Wt[144 * 168];
    int tid = threadIdx.x;
    int wv = tid >> 6, ln = tid & 63;
    int m16 = ln & 15, quad = ln >> 4;
    int rowBase = blockIdx.x * 64 + wv * 16;
    int row = rowBase + m16;

    const bf16* const srcs[3] = {A0, A1, A2};
    const short8 zero8 = {0, 0, 0, 0, 0, 0, 0, 0};

    floatx4 acc[9];
    #pragma unroll
    for (int q = 0; q < 9; ++q) acc[q] = (floatx4){0.f, 0.f, 0.f, 0.f};

    #pragma unroll
    for (int ph = 0; ph < 3; ++ph) {
        __syncthreads();   // previous phase's readers done
        const uint4* Wg = (const uint4*)(wtb + ph * 144 * 168);   // 3024 uint4
        uint4* Wl = (uint4*)Wt;
        #pragma unroll
        for (int q = 0; q < 12; ++q) {
            int idx = q * 256 + tid;
            if (idx < 3024) Wl[idx] = Wg[idx];
        }
        __syncthreads();

        const bf16* A = srcs[ph];
        short8 a[5];
        #pragma unroll
        for (int kt = 0; kt < 5; ++kt) {
            int k0 = kt * 32 + quad * 8;
            if (k0 < FF && row < NN)
                a[kt] = *(const short8*)((const short*)A + row * FF + k0);
            else
                a[kt] = zero8;
        }

        #pragma unroll
        for (int nt = 0; nt < 9; ++nt) {
            #pragma unroll
            for (int kt = 0; kt < 5; ++kt) {
                short8 b = *(const short8*)&Wt[(nt * 16 + m16) * 168 + kt * 32 + quad * 8];
                acc[nt] = __builtin_amdgcn_mfma_f32_16x16x32_bf16(a[kt], b, acc[nt], 0, 0, 0);
            }
        }
    }

    int rowc = rowBase + quad * 4;
    #pragma unroll
    for (int nt = 0; nt < 9; ++nt) {
        int col = nt * 16 + m16;
        float bs = bias[col];
        #pragma unroll
        for (int r = 0; r < 4; ++r) {
            int rr = rowc + r;
            if (rr < NN) out[rr * FF + col] = acc[nt][r] + bs;
        }
    }
}

// ---------------- launch ----------------

extern "C" void kernel_launch(void* const* d_in, const int* in_sizes, int n_in,
                              void* d_out, int out_size, void* d_ws, size_t ws_size,
                              hipStream_t stream) {
    int ix = -1, iei = -1, iew = -1, iwt = -1, ib = -1;
    for (int i = 0; i < n_in; ++i) {
        switch (in_sizes[i]) {
            case NN * FF:      if (ix  < 0) ix  = i; break;
            case 2 * EE:       if (iei < 0) iei = i; break;
            case EE:           if (iew < 0) iew = i; break;
            case 3 * FF * FF:  if (iwt < 0) iwt = i; break;
            case FF:           if (ib  < 0) ib  = i; break;
        }
    }
    if (ix < 0 || iei < 0 || iew < 0 || iwt < 0 || ib < 0) {
        ix = 0; iei = 1; iew = 2; iwt = 3; ib = 4;
    }
    const float* x    = (const float*)d_in[ix];
    const int*   ei   = (const int*)d_in[iei];
    const float* ew   = (const float*)d_in[iew];
    const float* wt   = (const float*)d_in[iwt];
    const float* bias = (const float*)d_in[ib];
    float* out = (float*)d_out;   // reference output dtype is float32

    char* p = (char*)d_ws;
    int*   cnt    = (int*)(p + 0);
    int*   fill   = (int*)(p + 200000);
    int*   rowptr = (int*)(p + 400000);
    float* dinv   = (float*)(p + 600016);
    int*   cols   = (int*)(p + 800016);
    float* lap    = (float*)(p + 4000016);
    bf16*  tx1    = (bf16*)(p + 7200016);
    bf16*  tx2    = (bf16*)(p + 21600016);
    short* wtb    = (short*)(p + 36000016);  // 3*144*168 shorts = 145,152 B (in old accb hole)
    bf16*  xb     = (bf16*)(p + 64800016);
    int*   eflag  = (int*)(p + 79200016);

    if (ws_size < 79200032) return;

    hipMemsetAsync(d_ws, 0, 400000, stream);  // cnt + fill

    int ewGrid   = (NN * FF + 255) / 256;
    int spGrid   = (NN * 18 + 255) / 256;
    int gemmGrid = (NN + 63) / 64;
    int wGrid    = (3 * FF * 168 + 255) / 256;

    detect_k<<<1, 256, 0, stream>>>(ei, eflag);
    cvt_k<<<ewGrid, 256, 0, stream>>>(x, xb);
    cvtw_k<<<wGrid, 256, 0, stream>>>(wt, wtb);
    hist_k<<<(EE + 255) / 256, 256, 0, stream>>>(ei, cnt, eflag);
    dinv_k<<<(NN + 255) / 256, 256, 0, stream>>>(cnt, dinv);
    scan_k<<<1, 1024, 0, stream>>>(cnt, rowptr);
    scatter_k<<<(EE + 255) / 256, 256, 0, stream>>>(ei, ew, dinv, rowptr, fill, cols, lap, eflag);

    spmm_k<0><<<spGrid, 256, 0, stream>>>(xb, xb, rowptr, cols, lap, tx1);
    spmm_k<1><<<spGrid, 256, 0, stream>>>(tx1, xb, rowptr, cols, lap, tx2);
    gemm_fused<<<gemmGrid, 256, 0, stream>>>(xb, tx1, tx2, wtb, bias, out);
}

// Round 14
// 309.121 us; speedup vs baseline: 2.5830x; 1.1446x over previous
//
#include <hip/hip_runtime.h>
#include <hip/hip_bf16.h>

#define NN 50000
#define EE 800000
#define FF 144
#define NBLK 196   // ceil(NN/256)

typedef __hip_bfloat16 bf16;
typedef __attribute__((ext_vector_type(8))) short short8;
typedef __attribute__((ext_vector_type(4))) float floatx4;

__device__ inline float blo(unsigned x) { return __uint_as_float(x << 16); }
__device__ inline float bhi(unsigned x) { return __uint_as_float(x & 0xffff0000u); }

// ---------------- edge_index int64-layout detection ----------------

__global__ void detect_k(const int* __restrict__ ei, int* __restrict__ flag) {
    __shared__ int nz;
    if (threadIdx.x == 0) nz = 0;
    __syncthreads();
    if (ei[2 * threadIdx.x + 1] != 0) atomicAdd(&nz, 1);
    __syncthreads();
    if (threadIdx.x == 0) *flag = (nz == 0) ? 1 : 0;
}

__device__ inline void load_edge(const int* ei, int e, int flag, int& r, int& c) {
    if (flag) { r = ei[2 * e]; c = ei[2 * EE + 2 * e]; }
    else      { r = ei[e];     c = ei[EE + e]; }
}

// ---------------- x fp32 -> bf16 ----------------

__global__ void cvt_k(const float* __restrict__ x, bf16* __restrict__ xb) {
    int t = blockIdx.x * 256 + threadIdx.x;
    if (t >= NN * FF) return;
    xb[t] = (bf16)x[t];
}

// ---------------- W fp32 (K,i,o) -> bf16 transposed padded image wtb[ph][o][i] ----------------

__global__ void cvtw_k(const float* __restrict__ wt, short* __restrict__ wtb) {
    int t = blockIdx.x * 256 + threadIdx.x;
    if (t >= 3 * FF * 168) return;
    int ph = t / (FF * 168);
    int rem = t - ph * FF * 168;
    int o = rem / 168;
    int i = rem - o * 168;
    short v = 0;
    if (i < FF) {
        bf16 b = (bf16)wt[ph * FF * FF + i * FF + o];
        v = *(const short*)&b;
    }
    wtb[t] = v;
}

// ---------------- graph preprocessing ----------------

__global__ void hist_k(const int* __restrict__ ei, int* __restrict__ cnt,
                       const int* __restrict__ flagp) {
    int flag = *flagp;
    int e = blockIdx.x * 256 + threadIdx.x;
    if (e >= EE) return;
    int r, c; load_edge(ei, e, flag, r, c);
    if (r != c) atomicAdd(&cnt[r], 1);
}

__global__ void dinv_k(const int* __restrict__ cnt, float* __restrict__ dinv) {
    int i = blockIdx.x * 256 + threadIdx.x;
    if (i >= NN) return;
    int c = cnt[i];
    dinv[i] = c > 0 ? rsqrtf((float)c) : 0.f;
}

// ---------------- multi-block exclusive scan: cnt -> rowptr ----------------
// phase 1: per-block local exclusive scan + block sums
__global__ void scan1_k(const int* __restrict__ cnt, int* __restrict__ rowptr,
                        int* __restrict__ bsum) {
    __shared__ int wsum[4], woff[4];
    int b = blockIdx.x, tid = threadIdx.x;
    int wv = tid >> 6, ln = tid & 63;
    int i = b * 256 + tid;
    int v = (i < NN) ? cnt[i] : 0;
    int x = v;
    #pragma unroll
    for (int off = 1; off < 64; off <<= 1) {
        int t = __shfl_up(x, off, 64);
        if (ln >= off) x += t;
    }
    if (ln == 63) wsum[wv] = x;
    __syncthreads();
    if (tid == 0) {
        int s = 0;
        #pragma unroll
        for (int j = 0; j < 4; ++j) { woff[j] = s; s += wsum[j]; }
        bsum[b] = s;
    }
    __syncthreads();
    if (i < NN) rowptr[i] = woff[wv] + (x - v);
}

// phase 2: scan the 196 block sums (1 block), write rowptr[NN] = grand total
__global__ void scan2_k(int* __restrict__ bsum, int* __restrict__ rowptr) {
    __shared__ int wsum[4], woff[4];
    int tid = threadIdx.x;
    int wv = tid >> 6, ln = tid & 63;
    int v = (tid < NBLK) ? bsum[tid] : 0;
    int x = v;
    #pragma unroll
    for (int off = 1; off < 64; off <<= 1) {
        int t = __shfl_up(x, off, 64);
        if (ln >= off) x += t;
    }
    if (ln == 63) wsum[wv] = x;
    __syncthreads();
    if (tid == 0) {
        int s = 0;
        #pragma unroll
        for (int j = 0; j < 4; ++j) { woff[j] = s; s += wsum[j]; }
        rowptr[NN] = s;
    }
    __syncthreads();
    if (tid < NBLK) bsum[tid] = woff[wv] + (x - v);
}

// phase 3: add block offsets
__global__ void scan3_k(int* __restrict__ rowptr, const int* __restrict__ bsum) {
    int b = blockIdx.x;
    int i = b * 256 + threadIdx.x;
    if (i < NN) rowptr[i] += bsum[b];
}

// ---------------- scatter: packed (col, lap) int2 per edge ----------------

__global__ void scatter_k(const int* __restrict__ ei, const float* __restrict__ w,
                          const float* __restrict__ dinv, const int* __restrict__ rowptr,
                          int* __restrict__ fill, int2* __restrict__ pairs,
                          const int* __restrict__ flagp) {
    int flag = *flagp;
    int e = blockIdx.x * 256 + threadIdx.x;
    if (e >= EE) return;
    int r, c; load_edge(ei, e, flag, r, c);
    if (r == c) return;
    int pos = rowptr[r] + atomicAdd(&fill[r], 1);
    int2 pr;
    pr.x = c;
    pr.y = __float_as_int(-dinv[r] * dinv[c] * w[e]);
    pairs[pos] = pr;
}

// ---------------- SpMM 8-wide, packed edge stream, unrolled x2 ----------------

template <int MODE>
__global__ void spmm_k(const bf16* __restrict__ v, const bf16* __restrict__ x0,
                       const int* __restrict__ rowptr, const int2* __restrict__ pairs,
                       bf16* __restrict__ y) {
    int t = blockIdx.x * 256 + threadIdx.x;
    if (t >= NN * 18) return;
    int i = t / 18;
    int f8 = (t - i * 18) * 8;
    const unsigned short* vp = (const unsigned short*)v + f8;

    float a[8];
    #pragma unroll
    for (int j = 0; j < 8; ++j) a[j] = 0.f;

    int s = rowptr[i], e = rowptr[i + 1];
    int p = s;
    for (; p + 1 < e; p += 2) {
        int2 pr0 = pairs[p], pr1 = pairs[p + 1];
        float l0 = __int_as_float(pr0.y), l1 = __int_as_float(pr1.y);
        uint4 u0 = *(const uint4*)(vp + pr0.x * FF);
        uint4 u1 = *(const uint4*)(vp + pr1.x * FF);
        a[0] = fmaf(l0, blo(u0.x), a[0]);  a[1] = fmaf(l0, bhi(u0.x), a[1]);
        a[2] = fmaf(l0, blo(u0.y), a[2]);  a[3] = fmaf(l0, bhi(u0.y), a[3]);
        a[4] = fmaf(l0, blo(u0.z), a[4]);  a[5] = fmaf(l0, bhi(u0.z), a[5]);
        a[6] = fmaf(l0, blo(u0.w), a[6]);  a[7] = fmaf(l0, bhi(u0.w), a[7]);
        a[0] = fmaf(l1, blo(u1.x), a[0]);  a[1] = fmaf(l1, bhi(u1.x), a[1]);
        a[2] = fmaf(l1, blo(u1.y), a[2]);  a[3] = fmaf(l1, bhi(u1.y), a[3]);
        a[4] = fmaf(l1, blo(u1.z), a[4]);  a[5] = fmaf(l1, bhi(u1.z), a[5]);
        a[6] = fmaf(l1, blo(u1.w), a[6]);  a[7] = fmaf(l1, bhi(u1.w), a[7]);
    }
    if (p < e) {
        int2 pr = pairs[p];
        float l = __int_as_float(pr.y);
        uint4 u = *(const uint4*)(vp + pr.x * FF);
        a[0] = fmaf(l, blo(u.x), a[0]);  a[1] = fmaf(l, bhi(u.x), a[1]);
        a[2] = fmaf(l, blo(u.y), a[2]);  a[3] = fmaf(l, bhi(u.y), a[3]);
        a[4] = fmaf(l, blo(u.z), a[4]);  a[5] = fmaf(l, bhi(u.z), a[5]);
        a[6] = fmaf(l, blo(u.w), a[6]);  a[7] = fmaf(l, bhi(u.w), a[7]);
    }

    if (MODE == 1) {
        uint4 u0 = *(const uint4*)((const unsigned short*)x0 + i * FF + f8);
        a[0] = 2.f * a[0] - blo(u0.x);  a[1] = 2.f * a[1] - bhi(u0.x);
        a[2] = 2.f * a[2] - blo(u0.y);  a[3] = 2.f * a[3] - bhi(u0.y);
        a[4] = 2.f * a[4] - blo(u0.z);  a[5] = 2.f * a[5] - bhi(u0.z);
        a[6] = 2.f * a[6] - blo(u0.w);  a[7] = 2.f * a[7] - bhi(u0.w);
    }

    unsigned short rs[8];
    #pragma unroll
    for (int j = 0; j < 8; ++j) {
        bf16 b = (bf16)a[j];
        rs[j] = *(unsigned short*)&b;
    }
    *(uint4*)((unsigned short*)y + i * FF + f8) = *(uint4*)rs;
}

// ---------------- fused MFMA GEMM (unchanged from r13 passing version) ----------------

__global__ __launch_bounds__(256)
void gemm_fused(const bf16* __restrict__ A0, const bf16* __restrict__ A1,
                const bf16* __restrict__ A2, const short* __restrict__ wtb,
                const float* __restrict__ bias, float* __restrict__ out) {
    __shared__ __align__(16) short Wt[144 * 168];
    int tid = threadIdx.x;
    int wv = tid >> 6, ln = tid & 63;
    int m16 = ln & 15, quad = ln >> 4;
    int rowBase = blockIdx.x * 64 + wv * 16;
    int row = rowBase + m16;

    const bf16* const srcs[3] = {A0, A1, A2};
    const short8 zero8 = {0, 0, 0, 0, 0, 0, 0, 0};

    floatx4 acc[9];
    #pragma unroll
    for (int q = 0; q < 9; ++q) acc[q] = (floatx4){0.f, 0.f, 0.f, 0.f};

    #pragma unroll
    for (int ph = 0; ph < 3; ++ph) {
        __syncthreads();
        const uint4* Wg = (const uint4*)(wtb + ph * 144 * 168);   // 3024 uint4
        uint4* Wl = (uint4*)Wt;
        #pragma unroll
        for (int q = 0; q < 12; ++q) {
            int idx = q * 256 + tid;
            if (idx < 3024) Wl[idx] = Wg[idx];
        }
        __syncthreads();

        const bf16* A = srcs[ph];
        short8 a[5];
        #pragma unroll
        for (int kt = 0; kt < 5; ++kt) {
            int k0 = kt * 32 + quad * 8;
            if (k0 < FF && row < NN)
                a[kt] = *(const short8*)((const short*)A + row * FF + k0);
            else
                a[kt] = zero8;
        }

        #pragma unroll
        for (int nt = 0; nt < 9; ++nt) {
            #pragma unroll
            for (int kt = 0; kt < 5; ++kt) {
                short8 b = *(const short8*)&Wt[(nt * 16 + m16) * 168 + kt * 32 + quad * 8];
                acc[nt] = __builtin_amdgcn_mfma_f32_16x16x32_bf16(a[kt], b, acc[nt], 0, 0, 0);
            }
        }
    }

    int rowc = rowBase + quad * 4;
    #pragma unroll
    for (int nt = 0; nt < 9; ++nt) {
        int col = nt * 16 + m16;
        float bs = bias[col];
        #pragma unroll
        for (int r = 0; r < 4; ++r) {
            int rr = rowc + r;
            if (rr < NN) out[rr * FF + col] = acc[nt][r] + bs;
        }
    }
}

// ---------------- launch ----------------

extern "C" void kernel_launch(void* const* d_in, const int* in_sizes, int n_in,
                              void* d_out, int out_size, void* d_ws, size_t ws_size,
                              hipStream_t stream) {
    int ix = -1, iei = -1, iew = -1, iwt = -1, ib = -1;
    for (int i = 0; i < n_in; ++i) {
        switch (in_sizes[i]) {
            case NN * FF:      if (ix  < 0) ix  = i; break;
            case 2 * EE:       if (iei < 0) iei = i; break;
            case EE:           if (iew < 0) iew = i; break;
            case 3 * FF * FF:  if (iwt < 0) iwt = i; break;
            case FF:           if (ib  < 0) ib  = i; break;
        }
    }
    if (ix < 0 || iei < 0 || iew < 0 || iwt < 0 || ib < 0) {
        ix = 0; iei = 1; iew = 2; iwt = 3; ib = 4;
    }
    const float* x    = (const float*)d_in[ix];
    const int*   ei   = (const int*)d_in[iei];
    const float* ew   = (const float*)d_in[iew];
    const float* wt   = (const float*)d_in[iwt];
    const float* bias = (const float*)d_in[ib];
    float* out = (float*)d_out;   // reference output dtype is float32

    char* p = (char*)d_ws;
    int*   cnt    = (int*)(p + 0);           // N ints
    int*   fill   = (int*)(p + 200000);      // N ints
    int*   rowptr = (int*)(p + 400000);      // N+1 ints
    float* dinv   = (float*)(p + 600016);    // N floats
    int2*  pairs  = (int2*)(p + 800016);     // E int2 (col, lap) = 6.4 MB, 8B-aligned
    bf16*  tx1    = (bf16*)(p + 7200016);
    bf16*  tx2    = (bf16*)(p + 21600016);
    short* wtb    = (short*)(p + 36000016);  // 3*144*168 shorts
    int*   bsum   = (int*)(p + 36200000);    // NBLK ints (scan block sums)
    bf16*  xb     = (bf16*)(p + 64800016);
    int*   eflag  = (int*)(p + 79200016);

    if (ws_size < 79200032) return;

    hipMemsetAsync(d_ws, 0, 400000, stream);  // cnt + fill

    int ewGrid   = (NN * FF + 255) / 256;
    int spGrid   = (NN * 18 + 255) / 256;
    int gemmGrid = (NN + 63) / 64;
    int wGrid    = (3 * FF * 168 + 255) / 256;

    detect_k<<<1, 256, 0, stream>>>(ei, eflag);
    cvt_k<<<ewGrid, 256, 0, stream>>>(x, xb);
    cvtw_k<<<wGrid, 256, 0, stream>>>(wt, wtb);
    hist_k<<<(EE + 255) / 256, 256, 0, stream>>>(ei, cnt, eflag);
    dinv_k<<<(NN + 255) / 256, 256, 0, stream>>>(cnt, dinv);
    scan1_k<<<NBLK, 256, 0, stream>>>(cnt, rowptr, bsum);
    scan2_k<<<1, 256, 0, stream>>>(bsum, rowptr);
    scan3_k<<<NBLK, 256, 0, stream>>>(rowptr, bsum);
    scatter_k<<<(EE + 255) / 256, 256, 0, stream>>>(ei, ew, dinv, rowptr, fill, pairs, eflag);

    spmm_k<0><<<spGrid, 256, 0, stream>>>(xb, xb, rowptr, pairs, tx1);
    spmm_k<1><<<spGrid, 256, 0, stream>>>(tx1, xb, rowptr, pairs, tx2);
    gemm_fused<<<gemmGrid, 256, 0, stream>>>(xb, tx1, tx2, wtb, bias, out);
}